// Round 4
// baseline (352.669 us; speedup 1.0000x reference)
//
#include <hip/hip_runtime.h>
#include <stdint.h>

#define DEVINL __device__ __forceinline__

typedef __attribute__((ext_vector_type(8))) __bf16 bf16x8;
typedef __attribute__((ext_vector_type(4))) float f32x4;
typedef __attribute__((ext_vector_type(16))) float f32x16;
typedef __attribute__((ext_vector_type(4))) int i32x4;
typedef __attribute__((ext_vector_type(8))) int i32x8;

// ---------- helpers ----------
DEVINL unsigned short f2bf(float f) {
  union { float f; unsigned int u; } v; v.f = f;
  unsigned int u = v.u;
  return (unsigned short)((u + 0x7fffu + ((u >> 16) & 1u)) >> 16);  // RNE
}

// float -> OCP e4m3 byte via HW cvt (gfx950 = OCP semantics)
DEVINL unsigned char f2fp8(float f) {
  return (unsigned char)(__builtin_amdgcn_cvt_pk_fp8_f32(f, f, 0, false) & 0xff);
}

DEVINL float sigm(float x) { return __builtin_amdgcn_rcpf(1.f + __expf(-x)); }
// tanh = 1 - 2/(1+e^{2x}); inf-safe both directions.
DEVINL float tanh_(float x) {
  return 1.f - 2.f * __builtin_amdgcn_rcpf(1.f + __expf(2.f * x));
}

// Operand-order ("tiled") global layout for gemm2's fp8 operands.
// 2048-B panel per (32-row block, 64-k block): [h=(k>>4)&1][g=(k>>5)&1][row&31][k&15]
// One staging instruction (fixed rowblk, kt, h) then reads 1024 CONTIGUOUS
// bytes with source byte = lane*16 (lane = g*32 + row), matching the HW's
// dest scatter exactly -> coalesced staging AND conflict-free lane-linear
// LDS reads (R3's layout scattered the staging 64-way; this removes it).
DEVINL size_t opt_off(int row, int k) {
  return (size_t)((row >> 5) * 8 + (k >> 6)) * 2048 + ((k >> 4) & 1) * 1024 +
         ((k >> 5) & 1) * 512 + (row & 31) * 16 + (k & 15);
}

// async global->LDS 16B per lane; lds base wave-uniform, HW scatters lane i to base+i*16
#define GLD_LDS16(gptr, lptr)                                                  \
  __builtin_amdgcn_global_load_lds(                                            \
      (__attribute__((address_space(1))) void*)(gptr),                         \
      (__attribute__((address_space(3))) void*)(lptr), 16, 0, 0)

// Stage-before-barrier pipeline: STAGE(k+1) issued BEFORE the top barrier;
// TOPBAR_N waits vmcnt(N) = one stage's loads -> stage k landed, stage k+1
// crosses the barrier in flight. Last iter peels to vmcnt(0).
#define TOPBAR_6 asm volatile("s_waitcnt vmcnt(6) lgkmcnt(0)\n\ts_barrier" ::: "memory")
#define TOPBAR_4 asm volatile("s_waitcnt vmcnt(4) lgkmcnt(0)\n\ts_barrier" ::: "memory")
#define TOPBAR_1 asm volatile("s_waitcnt vmcnt(1) lgkmcnt(0)\n\ts_barrier" ::: "memory")
#define TOPBAR_0 asm volatile("s_waitcnt vmcnt(0) lgkmcnt(0)\n\ts_barrier" ::: "memory")
#define BOTBAR   asm volatile("s_waitcnt lgkmcnt(0)\n\ts_barrier" ::: "memory")

// bf16-path XOR swizzle (gemm1/gemm3, unchanged; measured 0-conflict): staging
// chunk c takes source chunk (c&3)^((c>>3)&3); read koff = (q ^ ((fr>>1)&3)).
DEVINL int swz_col(int c) { return ((c & 3) ^ ((c >> 3) & 3)) * 8; }   // bf16: *8 shorts = 16B

// ---------- fused prep: input concat + weight cvt + hvec, grid-sectioned ----------
__global__ void prep_all(const float* __restrict__ obs, const float* __restrict__ act,
                         const float* __restrict__ W1, const float* __restrict__ Wih,
                         const float* __restrict__ W2, const float* __restrict__ Whh,
                         const float* __restrict__ hid, const float* __restrict__ bhh,
                         const float* __restrict__ bih,
                         unsigned short* __restrict__ A0, unsigned short* __restrict__ W1b,
                         unsigned char* __restrict__ Wih8, unsigned short* __restrict__ W2b,
                         float* __restrict__ hvec) {
  const int bid = blockIdx.x, tid = threadIdx.x;
  if (bid < 2176) {
    // section A: concat(obs, act) -> bf16 [32768, 544]
    const int total = 32768 * 68;
    for (int c = bid * 256 + tid; c < total; c += 2176 * 256) {
      const int b = c / 68, c8 = c % 68;
      const float* src = (c8 < 64) ? (obs + (size_t)b * 512 + c8 * 8)
                                   : (act + (size_t)b * 32 + (c8 - 64) * 8);
      float4 f0 = *(const float4*)src;
      float4 f1 = *(const float4*)(src + 4);
      unsigned short u[8] = {f2bf(f0.x), f2bf(f0.y), f2bf(f0.z), f2bf(f0.w),
                             f2bf(f1.x), f2bf(f1.y), f2bf(f1.z), f2bf(f1.w)};
      *(uint4*)(A0 + (size_t)b * 544 + c8 * 8) = *(uint4*)u;
    }
  } else if (bid < 2176 + 1312) {
    // section B: weight conversion (one float4 per thread)
    const int i = (bid - 2176) * 256 + tid;
    if (i < 69632) {                       // W1 -> bf16
      float4 f = *(const float4*)(W1 + (size_t)i * 4);
      unsigned short u[4] = {f2bf(f.x), f2bf(f.y), f2bf(f.z), f2bf(f.w)};
      *(uint2*)(W1b + (size_t)i * 4) = *(uint2*)u;
    } else if (i < 69632 + 262144) {       // Wih -> fp8 e4m3 x16, operand-tiled layout
      const int off = i - 69632;
      const int row = off >> 7, col0 = (off & 127) * 4;  // 4 consecutive cols, same 16B chunk
      float4 f = *(const float4*)(Wih + (size_t)off * 4);
      int pk = __builtin_amdgcn_cvt_pk_fp8_f32(f.x * 16.f, f.y * 16.f, 0, false);
      pk = __builtin_amdgcn_cvt_pk_fp8_f32(f.z * 16.f, f.w * 16.f, pk, true);
      *(unsigned int*)(Wih8 + opt_off(row, col0)) = (unsigned int)pk;
    } else {                               // W2 -> bf16
      const int off = i - 331776;
      float4 f = *(const float4*)(W2 + (size_t)off * 4);
      unsigned short u[4] = {f2bf(f.x), f2bf(f.y), f2bf(f.z), f2bf(f.w)};
      *(uint2*)(W2b + (size_t)off * 4) = *(uint2*)u;
    }
  } else {
    // section C: hvec[j] = dot(W_hh[j,:], hid) + b_hh[j] + b_ih[j]
    const int j = (bid - 3488) * 4 + (tid >> 6);
    const int lane = tid & 63;
    const float* w = Whh + (size_t)j * 512;
    float s = 0.f;
    for (int k = lane; k < 512; k += 64) s += w[k] * hid[k];
    for (int off = 32; off; off >>= 1) s += __shfl_down(s, off, 64);
    if (lane == 0) hvec[j] = s + bhh[j] + bih[j];
  }
}

// ---------- GEMM1: X8 = fp8(relu(A0 @ W1^T + b1) * 8), operand-tiled out ----------
__global__ __launch_bounds__(256, 2) void gemm1_relu(
    const unsigned short* __restrict__ A0,   // [32768,544] bf16
    const unsigned short* __restrict__ W1b,  // [512,544] bf16
    const float* __restrict__ b1,            // [512]
    unsigned char* __restrict__ X8) {        // [32768,512] fp8 (x8, operand-tiled)
  constexpr int KT = 17, LD = 544;
  __shared__ __align__(16) unsigned short As[2][128 * 32];  // 16 KB
  __shared__ __align__(16) unsigned short Bs[2][128 * 32];  // 16 KB
  const int tid = threadIdx.x, wave = tid >> 6, lane = tid & 63;
  const int id = blockIdx.x, xcd = id & 7, slot = id >> 3;  // 1024 blocks
  const int m0 = (xcd * 32 + (slot >> 2)) * 128;            // 256 m-tiles
  const int n0 = (slot & 3) * 128;                          // 4 n-tiles
  const int wr = (wave >> 1) * 64, wc = (wave & 1) * 64;
  f32x4 acc[4][4] = {};

  const int c0 = tid, c1 = tid + 256;
  const unsigned short* pA0 = A0 + (size_t)(m0 + (c0 >> 2)) * LD + swz_col(c0);
  const unsigned short* pA1 = A0 + (size_t)(m0 + (c1 >> 2)) * LD + swz_col(c1);
  const unsigned short* pB0 = W1b + (size_t)(n0 + (c0 >> 2)) * LD + swz_col(c0);
  const unsigned short* pB1 = W1b + (size_t)(n0 + (c1 >> 2)) * LD + swz_col(c1);
  const int fr = lane & 15, q = lane >> 4;
  const int koff = (q ^ ((fr >> 1) & 3)) * 8;

#define STAGE1(buf)                                                            \
  do {                                                                         \
    GLD_LDS16(pA0, &As[(buf)][wave * 512]);                                    \
    GLD_LDS16(pA1, &As[(buf)][2048 + wave * 512]);                             \
    GLD_LDS16(pB0, &Bs[(buf)][wave * 512]);                                    \
    GLD_LDS16(pB1, &Bs[(buf)][2048 + wave * 512]);                             \
    pA0 += 32; pA1 += 32; pB0 += 32; pB1 += 32;                                \
  } while (0)

  STAGE1(0);
  for (int kt = 0; kt < KT; ++kt) {
    if (kt + 1 < KT) { STAGE1((kt + 1) & 1); TOPBAR_4; } else { TOPBAR_0; }
    const unsigned short* as = As[kt & 1];
    const unsigned short* bs = Bs[kt & 1];
    bf16x8 a[4], b[4];
#pragma unroll
    for (int i = 0; i < 4; ++i) a[i] = *(const bf16x8*)&as[(wr + i * 16 + fr) * 32 + koff];
#pragma unroll
    for (int j = 0; j < 4; ++j) b[j] = *(const bf16x8*)&bs[(wc + j * 16 + fr) * 32 + koff];
#pragma unroll
    for (int i = 0; i < 4; ++i)
#pragma unroll
      for (int j = 0; j < 4; ++j)
        acc[i][j] = __builtin_amdgcn_mfma_f32_16x16x32_bf16(a[i], b[j], acc[i][j], 0, 0, 0);
    BOTBAR;
  }
#undef STAGE1
  const int rbase = q * 4, cn = fr;
#pragma unroll
  for (int i = 0; i < 4; ++i)
#pragma unroll
    for (int j = 0; j < 4; ++j) {
      const int gn = n0 + wc + j * 16 + cn;
      const float bias = b1[gn];
#pragma unroll
      for (int r = 0; r < 4; ++r) {
        const int gm = m0 + wr + i * 16 + rbase + r;
        float v = acc[i][j][r] + bias;
        v = v > 0.f ? v : 0.f;
        X8[opt_off(gm, gn)] = f2fp8(v * 8.f);
      }
    }
}

// ---------- GEMM2 MX-fp8 32x32x64, BM=256, operand-order LDS + LSTM epilogue ----
// A = X8 (x8), B = Wih8 (x16), BOTH in operand-tiled global layout (opt_off);
// unit E8M0 scales; acc * (1/128) restores scale. Wave owns 64 rows (2 A-frags)
// x 32 cols x 4 gate quadrants: per kt = 12 b128 reads / 8 MFMAs.
//
// LDS byte layout (dest of gload_lds, linear as HW requires):
//   A: wave*4096 + frag*2048 + half*1024 + lane*16
//   B: quad*2048 +              half*1024 + lane*16
// Each staging instruction reads 1024 CONTIGUOUS global bytes (src = base +
// lane*16, identical to dest scatter) -> fully coalesced; reads are lane-linear
// stride-16 -> zero bank conflicts (measured 0 in R3 with this read pattern).
// Operand layout (32x32x64 f8f6f4): lane l holds row l&31, k=(l>>5)*32+[0..31].
// C/D: col=lane&31, row=(reg&3)+8*(reg>>2)+4*(lane>>5)  (shape-determined).
__global__ __launch_bounds__(256, 3) void gemm2_lstm(
    const unsigned char* __restrict__ X8,    // [32768,512] fp8, operand-tiled
    const unsigned char* __restrict__ Wih8,  // [2048,512] fp8, operand-tiled
    const float* __restrict__ hvec,          // [2048]
    const float* __restrict__ cell,          // [512]
    unsigned short* __restrict__ H,          // [32768,512] bf16 out
    float* __restrict__ hlast,               // [512] fp32 out
    float* __restrict__ clast) {             // [512] fp32 out
  constexpr int KT = 8;                      // BK = 64
  __shared__ __align__(16) unsigned char As[2][256 * 64];     // 16 KB each buf
  __shared__ __align__(16) unsigned char Bs[2][4 * 32 * 64];  // 8 KB each buf
  const int tid = threadIdx.x, wave = tid >> 6, lane = tid & 63;
  const int id = blockIdx.x, xcd = id & 7, slot = id >> 3;  // 2048 blocks
  const int m0 = (xcd * 16 + (slot >> 4)) * 256;            // 128 m-tiles
  const int n0 = (slot & 15) * 32;                          // 16 quadrant-col tiles
  // 8 accumulators: [frag f=0,1][gate quadrant 0..3], named for static alloc
  f32x16 acc00 = {}, acc01 = {}, acc02 = {}, acc03 = {};
  f32x16 acc10 = {}, acc11 = {}, acc12 = {}, acc13 = {};

  const int r31 = lane & 31, g2 = lane >> 5;
  const int fA = wave >> 1, hA = wave & 1;
  // Staging sources in tiled layout: instruction (region j, stage-wave) covers
  // rowblk = (m0>>5) + j*2 + fA (A) / quad*16 + n0>>5 (B), k-block kt, half hA;
  // 1024 contiguous bytes, lane part = lane*16. Advance +2048 per kt.
  const unsigned char* pA0 = X8 + (size_t)((m0 >> 5) + 0 + fA) * 16384 + hA * 1024 + lane * 16;
  const unsigned char* pA1 = X8 + (size_t)((m0 >> 5) + 2 + fA) * 16384 + hA * 1024 + lane * 16;
  const unsigned char* pA2 = X8 + (size_t)((m0 >> 5) + 4 + fA) * 16384 + hA * 1024 + lane * 16;
  const unsigned char* pA3 = X8 + (size_t)((m0 >> 5) + 6 + fA) * 16384 + hA * 1024 + lane * 16;
  const unsigned char* pB0 =
      Wih8 + (size_t)((0 + fA) * 16 + (n0 >> 5)) * 16384 + hA * 1024 + lane * 16;
  const unsigned char* pB1 =
      Wih8 + (size_t)((2 + fA) * 16 + (n0 >> 5)) * 16384 + hA * 1024 + lane * 16;

  const int lb = lane * 16;  // lane-linear read base (conflict-free)

#define STAGE2(buf)                                                            \
  do {                                                                         \
    GLD_LDS16(pA0, &As[(buf)][wave * 1024]);                                   \
    GLD_LDS16(pA1, &As[(buf)][4096 + wave * 1024]);                            \
    GLD_LDS16(pA2, &As[(buf)][8192 + wave * 1024]);                            \
    GLD_LDS16(pA3, &As[(buf)][12288 + wave * 1024]);                           \
    GLD_LDS16(pB0, &Bs[(buf)][wave * 1024]);                                   \
    GLD_LDS16(pB1, &Bs[(buf)][4096 + wave * 1024]);                            \
    pA0 += 2048; pA1 += 2048; pA2 += 2048; pA3 += 2048;                        \
    pB0 += 2048; pB1 += 2048;                                                  \
  } while (0)

#define LDPAIR(dst, base_ptr, off)                                             \
  do {                                                                         \
    i32x4 lo_ = *(const i32x4*)((base_ptr) + (off) + lb);                      \
    i32x4 hi_ = *(const i32x4*)((base_ptr) + (off) + 1024 + lb);               \
    dst = __builtin_shufflevector(lo_, hi_, 0, 1, 2, 3, 4, 5, 6, 7);           \
  } while (0)

#define MFMA_MX(acc_, a_, b_)                                                  \
  acc_ = __builtin_amdgcn_mfma_scale_f32_32x32x64_f8f6f4(                      \
      a_, b_, acc_, 0, 0, 0, 0x7f7f7f7f, 0, 0x7f7f7f7f)

  STAGE2(0);
  for (int kt = 0; kt < KT; ++kt) {
    if (kt + 1 < KT) { STAGE2((kt + 1) & 1); TOPBAR_6; } else { TOPBAR_0; }
    const unsigned char* as = As[kt & 1];
    const unsigned char* bs = Bs[kt & 1];
    i32x8 b0, b1, b2, b3, a0, a1;
    LDPAIR(b0, bs, 0);
    LDPAIR(b1, bs, 2048);
    LDPAIR(b2, bs, 4096);
    LDPAIR(b3, bs, 6144);
    LDPAIR(a0, as, wave * 4096);
    LDPAIR(a1, as, wave * 4096 + 2048);
    MFMA_MX(acc00, a0, b0); MFMA_MX(acc01, a0, b1);
    MFMA_MX(acc02, a0, b2); MFMA_MX(acc03, a0, b3);
    MFMA_MX(acc10, a1, b0); MFMA_MX(acc11, a1, b1);
    MFMA_MX(acc12, a1, b2); MFMA_MX(acc13, a1, b3);
    BOTBAR;
  }
#undef STAGE2

  const int gn = n0 + r31;  // column in [0,512)
  const float hv_i = hvec[gn];
  const float hv_f = hvec[gn + 512];
  const float hv_g = hvec[gn + 1024];
  const float hv_o = hvec[gn + 1536];
  const float cprev = cell[gn];
  constexpr float S = 1.f / 128.f;  // undo x8 (X) * x16 (Wih)

#define EPILOG(F, ai, af, ag, ao)                                              \
  _Pragma("unroll")                                                            \
  for (int rg = 0; rg < 4; ++rg) {                                             \
    _Pragma("unroll")                                                          \
    for (int rr = 0; rr < 4; ++rr) {                                           \
      const int reg = rg * 4 + rr;                                             \
      const int gm = m0 + wave * 64 + (F) * 32 + rr + rg * 8 + g2 * 4;         \
      float si = sigm(ai[reg] * S + hv_i);                                     \
      float sf = sigm(af[reg] * S + hv_f);                                     \
      float tg = tanh_(ag[reg] * S + hv_g);                                    \
      float so = sigm(ao[reg] * S + hv_o);                                     \
      float cnew = sf * cprev + si * tg;                                       \
      float hnew = so * tanh_(cnew);                                           \
      H[(size_t)gm * 512 + gn] = f2bf(hnew);                                   \
      if (gm == 32767) { hlast[gn] = hnew; clast[gn] = cnew; }                 \
    }                                                                          \
  }

  EPILOG(0, acc00, acc01, acc02, acc03)
  EPILOG(1, acc10, acc11, acc12, acc13)
#undef EPILOG
#undef LDPAIR
#undef MFMA_MX
}

// ---------- GEMM3: Q = H @ W2^T + b2 (64-row tiles, 512 blocks) ----------
__global__ __launch_bounds__(256, 2) void gemm3(
    const unsigned short* __restrict__ H,    // [32768,512] bf16
    const unsigned short* __restrict__ W2b,  // [32,512] bf16
    const float* __restrict__ b2,            // [32]
    float* __restrict__ Q) {                 // [32768,32] fp32
  constexpr int KT = 16, LDW = 520;
  __shared__ __align__(16) unsigned short As[2][64 * 32];    // 8 KB
  __shared__ __align__(16) unsigned short Ws[32 * LDW];      // 32.5 KB
  const int tid = threadIdx.x, wave = tid >> 6, lane = tid & 63;
  const int id = blockIdx.x;                                 // 512 blocks
  const int m0 = ((id & 7) * 64 + (id >> 3)) * 64;           // 64-row tiles
  for (int c = tid; c < 2048; c += 256) {
    const int row = c >> 6, col8 = c & 63;
    *(uint4*)&Ws[row * LDW + col8 * 8] = *(const uint4*)(W2b + row * 512 + col8 * 8);
  }
  f32x4 acc[2] = {};
  const int c0 = tid;
  const unsigned short* pA0 = H + (size_t)(m0 + (c0 >> 2)) * 512 + swz_col(c0);
  const int fr = lane & 15, q = lane >> 4;
  const int koff = (q ^ ((fr >> 1) & 3)) * 8;

#define STAGE3(buf)                                                            \
  do {                                                                         \
    GLD_LDS16(pA0, &As[(buf)][wave * 512]);                                    \
    pA0 += 32;                                                                 \
  } while (0)

  STAGE3(0);
  for (int kt = 0; kt < KT; ++kt) {
    if (kt + 1 < KT) { STAGE3((kt + 1) & 1); TOPBAR_1; } else { TOPBAR_0; }
    const unsigned short* as = As[kt & 1];
    const int k0 = kt * 32;
    bf16x8 a  = *(const bf16x8*)&as[(wave * 16 + fr) * 32 + koff];
    bf16x8 b0 = *(const bf16x8*)&Ws[fr * LDW + k0 + q * 8];
    bf16x8 b1 = *(const bf16x8*)&Ws[(16 + fr) * LDW + k0 + q * 8];
    acc[0] = __builtin_amdgcn_mfma_f32_16x16x32_bf16(a, b0, acc[0], 0, 0, 0);
    acc[1] = __builtin_amdgcn_mfma_f32_16x16x32_bf16(a, b1, acc[1], 0, 0, 0);
    BOTBAR;
  }
#undef STAGE3
  const int rbase = q * 4;
#pragma unroll
  for (int j = 0; j < 2; ++j) {
    const int gn = j * 16 + fr;
    const float bias = b2[gn];
#pragma unroll
    for (int r = 0; r < 4; ++r) {
      const int gm = m0 + wave * 16 + rbase + r;
      Q[(size_t)gm * 32 + gn] = acc[j][r] + bias;
    }
  }
}

// ---------- launch ----------
extern "C" void kernel_launch(void* const* d_in, const int* in_sizes, int n_in,
                              void* d_out, int out_size, void* d_ws, size_t ws_size,
                              hipStream_t stream) {
  const float* obs  = (const float*)d_in[0];
  const float* act  = (const float*)d_in[1];
  const float* hid  = (const float*)d_in[2];
  const float* cell = (const float*)d_in[3];
  const float* W1   = (const float*)d_in[4];
  const float* b1   = (const float*)d_in[5];
  const float* Wih  = (const float*)d_in[6];
  const float* bih  = (const float*)d_in[7];
  const float* Whh  = (const float*)d_in[8];
  const float* bhh  = (const float*)d_in[9];
  const float* W2   = (const float*)d_in[10];
  const float* b2   = (const float*)d_in[11];
  float* out = (float*)d_out;

  char* ws = (char*)d_ws;
  unsigned short* A0   = (unsigned short*)(ws);              // [B,544] bf16 (35,651,584 B)
  unsigned short* H    = (unsigned short*)(ws);              // alias A0 (dead after gemm1)
  unsigned char*  X8   = (unsigned char*)(ws + 35651584);    // [B,512] fp8 tiled (16,777,216 B)
  unsigned short* W1b  = (unsigned short*)(ws + 52428800);   // 557,056 B
  unsigned char*  Wih8 = (unsigned char*)(ws + 52985856);    // 1,048,576 B
  unsigned short* W2b  = (unsigned short*)(ws + 54034432);   // 32,768 B
  float*          hvec = (float*)(ws + 54067200);            // 8,192 B

  prep_all<<<4000, 256, 0, stream>>>(obs, act, W1, Wih, W2, Whh, hid, bhh, bih,
                                     A0, W1b, Wih8, W2b, hvec);
  gemm1_relu<<<1024, 256, 0, stream>>>(A0, W1b, b1, X8);
  gemm2_lstm<<<2048, 256, 0, stream>>>(X8, Wih8, hvec, cell, H,
                                       out + 32768 * 32,
                                       out + 32768 * 32 + 512);
  gemm3<<<512, 256, 0, stream>>>(H, W2b, b2, out);
}

// Round 5
// 212.417 us; speedup vs baseline: 1.6603x; 1.6603x over previous
//
#include <hip/hip_runtime.h>
#include <stdint.h>

#define DEVINL __device__ __forceinline__

typedef __attribute__((ext_vector_type(8))) __bf16 bf16x8;
typedef __attribute__((ext_vector_type(4))) float f32x4;
typedef __attribute__((ext_vector_type(16))) float f32x16;
typedef __attribute__((ext_vector_type(4))) int i32x4;
typedef __attribute__((ext_vector_type(8))) int i32x8;

// ---------- helpers ----------
DEVINL unsigned short f2bf(float f) {
  union { float f; unsigned int u; } v; v.f = f;
  unsigned int u = v.u;
  return (unsigned short)((u + 0x7fffu + ((u >> 16) & 1u)) >> 16);  // RNE
}

// float -> OCP e4m3 byte via HW cvt (gfx950 = OCP semantics)
DEVINL unsigned char f2fp8(float f) {
  return (unsigned char)(__builtin_amdgcn_cvt_pk_fp8_f32(f, f, 0, false) & 0xff);
}

DEVINL float sigm(float x) { return __builtin_amdgcn_rcpf(1.f + __expf(-x)); }
// tanh = 1 - 2/(1+e^{2x}); inf-safe both directions.
DEVINL float tanh_(float x) {
  return 1.f - 2.f * __builtin_amdgcn_rcpf(1.f + __expf(2.f * x));
}

// Operand-order ("tiled") global layout for gemm2's fp8 operands.
// 2048-B panel per (32-row block, 64-k block): [h=(k>>4)&1][g=(k>>5)&1][row&31][k&15]
// One staging instruction (fixed rowblk, kt, h) then reads 1024 CONTIGUOUS
// bytes with source byte = lane*16 (lane = g*32 + row), matching the HW's
// dest scatter exactly -> coalesced staging AND conflict-free lane-linear
// LDS reads.
DEVINL size_t opt_off(int row, int k) {
  return (size_t)((row >> 5) * 8 + (k >> 6)) * 2048 + ((k >> 4) & 1) * 1024 +
         ((k >> 5) & 1) * 512 + (row & 31) * 16 + (k & 15);
}

// async global->LDS 16B per lane; lds base wave-uniform, HW scatters lane i to base+i*16
#define GLD_LDS16(gptr, lptr)                                                  \
  __builtin_amdgcn_global_load_lds(                                            \
      (__attribute__((address_space(1))) void*)(gptr),                         \
      (__attribute__((address_space(3))) void*)(lptr), 16, 0, 0)

// Stage-before-barrier pipeline: STAGE(k+1) issued BEFORE the top barrier;
// TOPBAR_N waits vmcnt(N) = one stage's loads -> stage k landed, stage k+1
// crosses the barrier in flight. Last iter peels to vmcnt(0).
#define TOPBAR_6 asm volatile("s_waitcnt vmcnt(6) lgkmcnt(0)\n\ts_barrier" ::: "memory")
#define TOPBAR_4 asm volatile("s_waitcnt vmcnt(4) lgkmcnt(0)\n\ts_barrier" ::: "memory")
#define TOPBAR_1 asm volatile("s_waitcnt vmcnt(1) lgkmcnt(0)\n\ts_barrier" ::: "memory")
#define TOPBAR_0 asm volatile("s_waitcnt vmcnt(0) lgkmcnt(0)\n\ts_barrier" ::: "memory")
#define BOTBAR   asm volatile("s_waitcnt lgkmcnt(0)\n\ts_barrier" ::: "memory")

// bf16-path XOR swizzle (gemm1/gemm3, unchanged; measured 0-conflict): staging
// chunk c takes source chunk (c&3)^((c>>3)&3); read koff = (q ^ ((fr>>1)&3)).
DEVINL int swz_col(int c) { return ((c & 3) ^ ((c >> 3) & 3)) * 8; }   // bf16: *8 shorts = 16B

// ---------- fused prep: input concat + weight cvt + hvec, grid-sectioned ----------
__global__ void prep_all(const float* __restrict__ obs, const float* __restrict__ act,
                         const float* __restrict__ W1, const float* __restrict__ Wih,
                         const float* __restrict__ W2, const float* __restrict__ Whh,
                         const float* __restrict__ hid, const float* __restrict__ bhh,
                         const float* __restrict__ bih,
                         unsigned short* __restrict__ A0, unsigned short* __restrict__ W1b,
                         unsigned char* __restrict__ Wih8, unsigned short* __restrict__ W2b,
                         float* __restrict__ hvec) {
  const int bid = blockIdx.x, tid = threadIdx.x;
  if (bid < 2176) {
    // section A: concat(obs, act) -> bf16 [32768, 544]
    const int total = 32768 * 68;
    for (int c = bid * 256 + tid; c < total; c += 2176 * 256) {
      const int b = c / 68, c8 = c % 68;
      const float* src = (c8 < 64) ? (obs + (size_t)b * 512 + c8 * 8)
                                   : (act + (size_t)b * 32 + (c8 - 64) * 8);
      float4 f0 = *(const float4*)src;
      float4 f1 = *(const float4*)(src + 4);
      unsigned short u[8] = {f2bf(f0.x), f2bf(f0.y), f2bf(f0.z), f2bf(f0.w),
                             f2bf(f1.x), f2bf(f1.y), f2bf(f1.z), f2bf(f1.w)};
      *(uint4*)(A0 + (size_t)b * 544 + c8 * 8) = *(uint4*)u;
    }
  } else if (bid < 2176 + 1312) {
    // section B: weight conversion (one float4 per thread)
    const int i = (bid - 2176) * 256 + tid;
    if (i < 69632) {                       // W1 -> bf16
      float4 f = *(const float4*)(W1 + (size_t)i * 4);
      unsigned short u[4] = {f2bf(f.x), f2bf(f.y), f2bf(f.z), f2bf(f.w)};
      *(uint2*)(W1b + (size_t)i * 4) = *(uint2*)u;
    } else if (i < 69632 + 262144) {       // Wih -> fp8 e4m3 x16, operand-tiled layout
      const int off = i - 69632;
      const int row = off >> 7, col0 = (off & 127) * 4;  // 4 consecutive cols, same 16B chunk
      float4 f = *(const float4*)(Wih + (size_t)off * 4);
      int pk = __builtin_amdgcn_cvt_pk_fp8_f32(f.x * 16.f, f.y * 16.f, 0, false);
      pk = __builtin_amdgcn_cvt_pk_fp8_f32(f.z * 16.f, f.w * 16.f, pk, true);
      *(unsigned int*)(Wih8 + opt_off(row, col0)) = (unsigned int)pk;
    } else {                               // W2 -> bf16
      const int off = i - 331776;
      float4 f = *(const float4*)(W2 + (size_t)off * 4);
      unsigned short u[4] = {f2bf(f.x), f2bf(f.y), f2bf(f.z), f2bf(f.w)};
      *(uint2*)(W2b + (size_t)off * 4) = *(uint2*)u;
    }
  } else {
    // section C: hvec[j] = dot(W_hh[j,:], hid) + b_hh[j] + b_ih[j]
    const int j = (bid - 3488) * 4 + (tid >> 6);
    const int lane = tid & 63;
    const float* w = Whh + (size_t)j * 512;
    float s = 0.f;
    for (int k = lane; k < 512; k += 64) s += w[k] * hid[k];
    for (int off = 32; off; off >>= 1) s += __shfl_down(s, off, 64);
    if (lane == 0) hvec[j] = s + bhh[j] + bih[j];
  }
}

// ---------- GEMM1: X8 = fp8(relu(A0 @ W1^T + b1) * 8), operand-tiled out ----------
__global__ __launch_bounds__(256, 2) void gemm1_relu(
    const unsigned short* __restrict__ A0,   // [32768,544] bf16
    const unsigned short* __restrict__ W1b,  // [512,544] bf16
    const float* __restrict__ b1,            // [512]
    unsigned char* __restrict__ X8) {        // [32768,512] fp8 (x8, operand-tiled)
  constexpr int KT = 17, LD = 544;
  __shared__ __align__(16) unsigned short As[2][128 * 32];  // 16 KB
  __shared__ __align__(16) unsigned short Bs[2][128 * 32];  // 16 KB
  const int tid = threadIdx.x, wave = tid >> 6, lane = tid & 63;
  const int id = blockIdx.x, xcd = id & 7, slot = id >> 3;  // 1024 blocks
  const int m0 = (xcd * 32 + (slot >> 2)) * 128;            // 256 m-tiles
  const int n0 = (slot & 3) * 128;                          // 4 n-tiles
  const int wr = (wave >> 1) * 64, wc = (wave & 1) * 64;
  f32x4 acc[4][4] = {};

  const int c0 = tid, c1 = tid + 256;
  const unsigned short* pA0 = A0 + (size_t)(m0 + (c0 >> 2)) * LD + swz_col(c0);
  const unsigned short* pA1 = A0 + (size_t)(m0 + (c1 >> 2)) * LD + swz_col(c1);
  const unsigned short* pB0 = W1b + (size_t)(n0 + (c0 >> 2)) * LD + swz_col(c0);
  const unsigned short* pB1 = W1b + (size_t)(n0 + (c1 >> 2)) * LD + swz_col(c1);
  const int fr = lane & 15, q = lane >> 4;
  const int koff = (q ^ ((fr >> 1) & 3)) * 8;

#define STAGE1(buf)                                                            \
  do {                                                                         \
    GLD_LDS16(pA0, &As[(buf)][wave * 512]);                                    \
    GLD_LDS16(pA1, &As[(buf)][2048 + wave * 512]);                             \
    GLD_LDS16(pB0, &Bs[(buf)][wave * 512]);                                    \
    GLD_LDS16(pB1, &Bs[(buf)][2048 + wave * 512]);                             \
    pA0 += 32; pA1 += 32; pB0 += 32; pB1 += 32;                                \
  } while (0)

  STAGE1(0);
  for (int kt = 0; kt < KT; ++kt) {
    if (kt + 1 < KT) { STAGE1((kt + 1) & 1); TOPBAR_4; } else { TOPBAR_0; }
    const unsigned short* as = As[kt & 1];
    const unsigned short* bs = Bs[kt & 1];
    bf16x8 a[4], b[4];
#pragma unroll
    for (int i = 0; i < 4; ++i) a[i] = *(const bf16x8*)&as[(wr + i * 16 + fr) * 32 + koff];
#pragma unroll
    for (int j = 0; j < 4; ++j) b[j] = *(const bf16x8*)&bs[(wc + j * 16 + fr) * 32 + koff];
#pragma unroll
    for (int i = 0; i < 4; ++i)
#pragma unroll
      for (int j = 0; j < 4; ++j)
        acc[i][j] = __builtin_amdgcn_mfma_f32_16x16x32_bf16(a[i], b[j], acc[i][j], 0, 0, 0);
    BOTBAR;
  }
#undef STAGE1
  const int rbase = q * 4, cn = fr;
#pragma unroll
  for (int i = 0; i < 4; ++i)
#pragma unroll
    for (int j = 0; j < 4; ++j) {
      const int gn = n0 + wc + j * 16 + cn;
      const float bias = b1[gn];
#pragma unroll
      for (int r = 0; r < 4; ++r) {
        const int gm = m0 + wr + i * 16 + rbase + r;
        float v = acc[i][j][r] + bias;
        v = v > 0.f ? v : 0.f;
        X8[opt_off(gm, gn)] = f2fp8(v * 8.f);
      }
    }
}

// ---------- GEMM2 MX-fp8 32x32x64, BM=256, operand-order LDS + LSTM epilogue ----
// A = X8 (x8), B = Wih8 (x16), BOTH in operand-tiled global layout (opt_off);
// unit E8M0 scales; acc * (1/128) restores scale. Wave owns 64 rows (2 A-frags)
// x 32 cols x 4 gate quadrants: per kt = 12 b128 reads / 8 MFMAs.
//
// LDS byte layout (dest of gload_lds, linear as HW requires):
//   A: wave*4096 + frag*2048 + half*1024 + lane*16
//   B: quad*2048 +              half*1024 + lane*16
// Each staging instruction reads 1024 CONTIGUOUS global bytes (src = base +
// lane*16, identical to dest scatter) -> fully coalesced; reads are lane-linear
// stride-16 -> zero bank conflicts (measured 0 in R3/R4 with this pattern).
//
// __launch_bounds__(256,2) is REQUIRED: 8 f32x16 accs = 128 regs + ~90 live
// VGPRs needs the 256-reg/wave budget. R4's (256,3) capped at ~170 -> acc
// spill to scratch (FETCH 295 MB, WRITE 600 MB, 3.3x slowdown). Do not raise.
// Operand layout (32x32x64 f8f6f4): lane l holds row l&31, k=(l>>5)*32+[0..31].
// C/D: col=lane&31, row=(reg&3)+8*(reg>>2)+4*(lane>>5)  (shape-determined).
__global__ __launch_bounds__(256, 2) void gemm2_lstm(
    const unsigned char* __restrict__ X8,    // [32768,512] fp8, operand-tiled
    const unsigned char* __restrict__ Wih8,  // [2048,512] fp8, operand-tiled
    const float* __restrict__ hvec,          // [2048]
    const float* __restrict__ cell,          // [512]
    unsigned short* __restrict__ H,          // [32768,512] bf16 out
    float* __restrict__ hlast,               // [512] fp32 out
    float* __restrict__ clast) {             // [512] fp32 out
  constexpr int KT = 8;                      // BK = 64
  __shared__ __align__(16) unsigned char As[2][256 * 64];     // 16 KB each buf
  __shared__ __align__(16) unsigned char Bs[2][4 * 32 * 64];  // 8 KB each buf
  const int tid = threadIdx.x, wave = tid >> 6, lane = tid & 63;
  const int id = blockIdx.x, xcd = id & 7, slot = id >> 3;  // 2048 blocks
  const int m0 = (xcd * 16 + (slot >> 4)) * 256;            // 128 m-tiles
  const int n0 = (slot & 15) * 32;                          // 16 quadrant-col tiles
  // 8 accumulators: [frag f=0,1][gate quadrant 0..3], named for static alloc
  f32x16 acc00 = {}, acc01 = {}, acc02 = {}, acc03 = {};
  f32x16 acc10 = {}, acc11 = {}, acc12 = {}, acc13 = {};

  const int r31 = lane & 31, g2 = lane >> 5;
  const int fA = wave >> 1, hA = wave & 1;
  // Staging sources in tiled layout: instruction (region j, stage-wave) covers
  // rowblk = (m0>>5) + j*2 + fA (A) / quad*16 + n0>>5 (B), k-block kt, half hA;
  // 1024 contiguous bytes, lane part = lane*16. Advance +2048 per kt.
  const unsigned char* pA0 = X8 + (size_t)((m0 >> 5) + 0 + fA) * 16384 + hA * 1024 + lane * 16;
  const unsigned char* pA1 = X8 + (size_t)((m0 >> 5) + 2 + fA) * 16384 + hA * 1024 + lane * 16;
  const unsigned char* pA2 = X8 + (size_t)((m0 >> 5) + 4 + fA) * 16384 + hA * 1024 + lane * 16;
  const unsigned char* pA3 = X8 + (size_t)((m0 >> 5) + 6 + fA) * 16384 + hA * 1024 + lane * 16;
  const unsigned char* pB0 =
      Wih8 + (size_t)((0 + fA) * 16 + (n0 >> 5)) * 16384 + hA * 1024 + lane * 16;
  const unsigned char* pB1 =
      Wih8 + (size_t)((2 + fA) * 16 + (n0 >> 5)) * 16384 + hA * 1024 + lane * 16;

  const int lb = lane * 16;  // lane-linear read base (conflict-free)

#define STAGE2(buf)                                                            \
  do {                                                                         \
    GLD_LDS16(pA0, &As[(buf)][wave * 1024]);                                   \
    GLD_LDS16(pA1, &As[(buf)][4096 + wave * 1024]);                            \
    GLD_LDS16(pA2, &As[(buf)][8192 + wave * 1024]);                            \
    GLD_LDS16(pA3, &As[(buf)][12288 + wave * 1024]);                           \
    GLD_LDS16(pB0, &Bs[(buf)][wave * 1024]);                                   \
    GLD_LDS16(pB1, &Bs[(buf)][4096 + wave * 1024]);                            \
    pA0 += 2048; pA1 += 2048; pA2 += 2048; pA3 += 2048;                        \
    pB0 += 2048; pB1 += 2048;                                                  \
  } while (0)

#define LDPAIR(dst, base_ptr, off)                                             \
  do {                                                                         \
    i32x4 lo_ = *(const i32x4*)((base_ptr) + (off) + lb);                      \
    i32x4 hi_ = *(const i32x4*)((base_ptr) + (off) + 1024 + lb);               \
    dst = __builtin_shufflevector(lo_, hi_, 0, 1, 2, 3, 4, 5, 6, 7);           \
  } while (0)

#define MFMA_MX(acc_, a_, b_)                                                  \
  acc_ = __builtin_amdgcn_mfma_scale_f32_32x32x64_f8f6f4(                      \
      a_, b_, acc_, 0, 0, 0, 0x7f7f7f7f, 0, 0x7f7f7f7f)

  STAGE2(0);
  for (int kt = 0; kt < KT; ++kt) {
    if (kt + 1 < KT) { STAGE2((kt + 1) & 1); TOPBAR_6; } else { TOPBAR_0; }
    const unsigned char* as = As[kt & 1];
    const unsigned char* bs = Bs[kt & 1];
    i32x8 b0, b1, b2, b3, a0, a1;
    LDPAIR(b0, bs, 0);
    LDPAIR(b1, bs, 2048);
    LDPAIR(b2, bs, 4096);
    LDPAIR(b3, bs, 6144);
    LDPAIR(a0, as, wave * 4096);
    LDPAIR(a1, as, wave * 4096 + 2048);
    MFMA_MX(acc00, a0, b0); MFMA_MX(acc01, a0, b1);
    MFMA_MX(acc02, a0, b2); MFMA_MX(acc03, a0, b3);
    MFMA_MX(acc10, a1, b0); MFMA_MX(acc11, a1, b1);
    MFMA_MX(acc12, a1, b2); MFMA_MX(acc13, a1, b3);
    BOTBAR;
  }
#undef STAGE2

  const int gn = n0 + r31;  // column in [0,512)
  const float hv_i = hvec[gn];
  const float hv_f = hvec[gn + 512];
  const float hv_g = hvec[gn + 1024];
  const float hv_o = hvec[gn + 1536];
  const float cprev = cell[gn];
  constexpr float S = 1.f / 128.f;  // undo x8 (X) * x16 (Wih)

#define EPILOG(F, ai, af, ag, ao)                                              \
  _Pragma("unroll")                                                            \
  for (int rg = 0; rg < 4; ++rg) {                                             \
    _Pragma("unroll")                                                          \
    for (int rr = 0; rr < 4; ++rr) {                                           \
      const int reg = rg * 4 + rr;                                             \
      const int gm = m0 + wave * 64 + (F) * 32 + rr + rg * 8 + g2 * 4;         \
      float si = sigm(ai[reg] * S + hv_i);                                     \
      float sf = sigm(af[reg] * S + hv_f);                                     \
      float tg = tanh_(ag[reg] * S + hv_g);                                    \
      float so = sigm(ao[reg] * S + hv_o);                                     \
      float cnew = sf * cprev + si * tg;                                       \
      float hnew = so * tanh_(cnew);                                           \
      H[(size_t)gm * 512 + gn] = f2bf(hnew);                                   \
      if (gm == 32767) { hlast[gn] = hnew; clast[gn] = cnew; }                 \
    }                                                                          \
  }

  EPILOG(0, acc00, acc01, acc02, acc03)
  EPILOG(1, acc10, acc11, acc12, acc13)
#undef EPILOG
#undef LDPAIR
#undef MFMA_MX
}

// ---------- GEMM3: Q = H @ W2^T + b2 (64-row tiles, 512 blocks) ----------
__global__ __launch_bounds__(256, 2) void gemm3(
    const unsigned short* __restrict__ H,    // [32768,512] bf16
    const unsigned short* __restrict__ W2b,  // [32,512] bf16
    const float* __restrict__ b2,            // [32]
    float* __restrict__ Q) {                 // [32768,32] fp32
  constexpr int KT = 16, LDW = 520;
  __shared__ __align__(16) unsigned short As[2][64 * 32];    // 8 KB
  __shared__ __align__(16) unsigned short Ws[32 * LDW];      // 32.5 KB
  const int tid = threadIdx.x, wave = tid >> 6, lane = tid & 63;
  const int id = blockIdx.x;                                 // 512 blocks
  const int m0 = ((id & 7) * 64 + (id >> 3)) * 64;           // 64-row tiles
  for (int c = tid; c < 2048; c += 256) {
    const int row = c >> 6, col8 = c & 63;
    *(uint4*)&Ws[row * LDW + col8 * 8] = *(const uint4*)(W2b + row * 512 + col8 * 8);
  }
  f32x4 acc[2] = {};
  const int c0 = tid;
  const unsigned short* pA0 = H + (size_t)(m0 + (c0 >> 2)) * 512 + swz_col(c0);
  const int fr = lane & 15, q = lane >> 4;
  const int koff = (q ^ ((fr >> 1) & 3)) * 8;

#define STAGE3(buf)                                                            \
  do {                                                                         \
    GLD_LDS16(pA0, &As[(buf)][wave * 512]);                                    \
    pA0 += 32;                                                                 \
  } while (0)

  STAGE3(0);
  for (int kt = 0; kt < KT; ++kt) {
    if (kt + 1 < KT) { STAGE3((kt + 1) & 1); TOPBAR_1; } else { TOPBAR_0; }
    const unsigned short* as = As[kt & 1];
    const int k0 = kt * 32;
    bf16x8 a  = *(const bf16x8*)&as[(wave * 16 + fr) * 32 + koff];
    bf16x8 b0 = *(const bf16x8*)&Ws[fr * LDW + k0 + q * 8];
    bf16x8 b1 = *(const bf16x8*)&Ws[(16 + fr) * LDW + k0 + q * 8];
    acc[0] = __builtin_amdgcn_mfma_f32_16x16x32_bf16(a, b0, acc[0], 0, 0, 0);
    acc[1] = __builtin_amdgcn_mfma_f32_16x16x32_bf16(a, b1, acc[1], 0, 0, 0);
    BOTBAR;
  }
#undef STAGE3
  const int rbase = q * 4;
#pragma unroll
  for (int j = 0; j < 2; ++j) {
    const int gn = j * 16 + fr;
    const float bias = b2[gn];
#pragma unroll
    for (int r = 0; r < 4; ++r) {
      const int gm = m0 + wave * 16 + rbase + r;
      Q[(size_t)gm * 32 + gn] = acc[j][r] + bias;
    }
  }
}

// ---------- launch ----------
extern "C" void kernel_launch(void* const* d_in, const int* in_sizes, int n_in,
                              void* d_out, int out_size, void* d_ws, size_t ws_size,
                              hipStream_t stream) {
  const float* obs  = (const float*)d_in[0];
  const float* act  = (const float*)d_in[1];
  const float* hid  = (const float*)d_in[2];
  const float* cell = (const float*)d_in[3];
  const float* W1   = (const float*)d_in[4];
  const float* b1   = (const float*)d_in[5];
  const float* Wih  = (const float*)d_in[6];
  const float* bih  = (const float*)d_in[7];
  const float* Whh  = (const float*)d_in[8];
  const float* bhh  = (const float*)d_in[9];
  const float* W2   = (const float*)d_in[10];
  const float* b2   = (const float*)d_in[11];
  float* out = (float*)d_out;

  char* ws = (char*)d_ws;
  unsigned short* A0   = (unsigned short*)(ws);              // [B,544] bf16 (35,651,584 B)
  unsigned short* H    = (unsigned short*)(ws);              // alias A0 (dead after gemm1)
  unsigned char*  X8   = (unsigned char*)(ws + 35651584);    // [B,512] fp8 tiled (16,777,216 B)
  unsigned short* W1b  = (unsigned short*)(ws + 52428800);   // 557,056 B
  unsigned char*  Wih8 = (unsigned char*)(ws + 52985856);    // 1,048,576 B
  unsigned short* W2b  = (unsigned short*)(ws + 54034432);   // 32,768 B
  float*          hvec = (float*)(ws + 54067200);            // 8,192 B

  prep_all<<<4000, 256, 0, stream>>>(obs, act, W1, Wih, W2, Whh, hid, bhh, bih,
                                     A0, W1b, Wih8, W2b, hvec);
  gemm1_relu<<<1024, 256, 0, stream>>>(A0, W1b, b1, X8);
  gemm2_lstm<<<2048, 256, 0, stream>>>(X8, Wih8, hvec, cell, H,
                                       out + 32768 * 32,
                                       out + 32768 * 32 + 512);
  gemm3<<<512, 256, 0, stream>>>(H, W2b, b2, out);
}

// Round 6
// 209.290 us; speedup vs baseline: 1.6851x; 1.0149x over previous
//
#include <hip/hip_runtime.h>
#include <stdint.h>

#define DEVINL __device__ __forceinline__

typedef __attribute__((ext_vector_type(8))) __bf16 bf16x8;
typedef __attribute__((ext_vector_type(4))) float f32x4;
typedef __attribute__((ext_vector_type(16))) float f32x16;
typedef __attribute__((ext_vector_type(4))) int i32x4;
typedef __attribute__((ext_vector_type(8))) int i32x8;

// ---------- helpers ----------
DEVINL unsigned short f2bf(float f) {
  union { float f; unsigned int u; } v; v.f = f;
  unsigned int u = v.u;
  return (unsigned short)((u + 0x7fffu + ((u >> 16) & 1u)) >> 16);  // RNE
}

// float -> OCP e4m3 byte via HW cvt (gfx950 = OCP semantics)
DEVINL unsigned char f2fp8(float f) {
  return (unsigned char)(__builtin_amdgcn_cvt_pk_fp8_f32(f, f, 0, false) & 0xff);
}

DEVINL float sigm(float x) { return __builtin_amdgcn_rcpf(1.f + __expf(-x)); }
// tanh = 1 - 2/(1+e^{2x}); inf-safe both directions.
DEVINL float tanh_(float x) {
  return 1.f - 2.f * __builtin_amdgcn_rcpf(1.f + __expf(2.f * x));
}

// Operand-order ("tiled") global layout for gemm2's fp8 operands.
// 2048-B panel per (32-row block, 64-k block): [h=(k>>4)&1][g=(k>>5)&1][row&31][k&15]
// Lane l (r31=l&31, g2=l>>5) of a 32x32x64 MFMA needs k = g2*32+[0..31]:
// lo 16B at panel + g2*512 + r31*16, hi 16B at +1024. A wave's 64 lanes cover
// 1024 contiguous bytes per half -> global_load_dwordx4 fully coalesced, and
// the bytes land DIRECTLY in MFMA operand order (no LDS needed at all).
DEVINL size_t opt_off(int row, int k) {
  return (size_t)((row >> 5) * 8 + (k >> 6)) * 2048 + ((k >> 4) & 1) * 1024 +
         ((k >> 5) & 1) * 512 + (row & 31) * 16 + (k & 15);
}

// async global->LDS 16B per lane; lds base wave-uniform, HW scatters lane i to base+i*16
#define GLD_LDS16(gptr, lptr)                                                  \
  __builtin_amdgcn_global_load_lds(                                            \
      (__attribute__((address_space(1))) void*)(gptr),                         \
      (__attribute__((address_space(3))) void*)(lptr), 16, 0, 0)

// Stage-before-barrier pipeline (gemm1/gemm3): STAGE(k+1) issued BEFORE the
// top barrier; TOPBAR_N waits vmcnt(N). Last iter peels to vmcnt(0).
#define TOPBAR_4 asm volatile("s_waitcnt vmcnt(4) lgkmcnt(0)\n\ts_barrier" ::: "memory")
#define TOPBAR_1 asm volatile("s_waitcnt vmcnt(1) lgkmcnt(0)\n\ts_barrier" ::: "memory")
#define TOPBAR_0 asm volatile("s_waitcnt vmcnt(0) lgkmcnt(0)\n\ts_barrier" ::: "memory")
#define BOTBAR   asm volatile("s_waitcnt lgkmcnt(0)\n\ts_barrier" ::: "memory")

// bf16-path XOR swizzle (gemm1/gemm3, unchanged; measured 0-conflict): staging
// chunk c takes source chunk (c&3)^((c>>3)&3); read koff = (q ^ ((fr>>1)&3)).
DEVINL int swz_col(int c) { return ((c & 3) ^ ((c >> 3) & 3)) * 8; }   // bf16: *8 shorts = 16B

// ---------- fused prep: input concat + weight cvt + hvec, grid-sectioned ----------
__global__ void prep_all(const float* __restrict__ obs, const float* __restrict__ act,
                         const float* __restrict__ W1, const float* __restrict__ Wih,
                         const float* __restrict__ W2, const float* __restrict__ Whh,
                         const float* __restrict__ hid, const float* __restrict__ bhh,
                         const float* __restrict__ bih,
                         unsigned short* __restrict__ A0, unsigned short* __restrict__ W1b,
                         unsigned char* __restrict__ Wih8, unsigned short* __restrict__ W2b,
                         float* __restrict__ hvec) {
  const int bid = blockIdx.x, tid = threadIdx.x;
  if (bid < 2176) {
    // section A: concat(obs, act) -> bf16 [32768, 544]
    const int total = 32768 * 68;
    for (int c = bid * 256 + tid; c < total; c += 2176 * 256) {
      const int b = c / 68, c8 = c % 68;
      const float* src = (c8 < 64) ? (obs + (size_t)b * 512 + c8 * 8)
                                   : (act + (size_t)b * 32 + (c8 - 64) * 8);
      float4 f0 = *(const float4*)src;
      float4 f1 = *(const float4*)(src + 4);
      unsigned short u[8] = {f2bf(f0.x), f2bf(f0.y), f2bf(f0.z), f2bf(f0.w),
                             f2bf(f1.x), f2bf(f1.y), f2bf(f1.z), f2bf(f1.w)};
      *(uint4*)(A0 + (size_t)b * 544 + c8 * 8) = *(uint4*)u;
    }
  } else if (bid < 2176 + 1312) {
    // section B: weight conversion (one float4 per thread)
    const int i = (bid - 2176) * 256 + tid;
    if (i < 69632) {                       // W1 -> bf16
      float4 f = *(const float4*)(W1 + (size_t)i * 4);
      unsigned short u[4] = {f2bf(f.x), f2bf(f.y), f2bf(f.z), f2bf(f.w)};
      *(uint2*)(W1b + (size_t)i * 4) = *(uint2*)u;
    } else if (i < 69632 + 262144) {       // Wih -> fp8 e4m3 x16, operand-tiled layout
      const int off = i - 69632;
      const int row = off >> 7, col0 = (off & 127) * 4;  // 4 consecutive cols, same 16B chunk
      float4 f = *(const float4*)(Wih + (size_t)off * 4);
      int pk = __builtin_amdgcn_cvt_pk_fp8_f32(f.x * 16.f, f.y * 16.f, 0, false);
      pk = __builtin_amdgcn_cvt_pk_fp8_f32(f.z * 16.f, f.w * 16.f, pk, true);
      *(unsigned int*)(Wih8 + opt_off(row, col0)) = (unsigned int)pk;
    } else {                               // W2 -> bf16
      const int off = i - 331776;
      float4 f = *(const float4*)(W2 + (size_t)off * 4);
      unsigned short u[4] = {f2bf(f.x), f2bf(f.y), f2bf(f.z), f2bf(f.w)};
      *(uint2*)(W2b + (size_t)off * 4) = *(uint2*)u;
    }
  } else {
    // section C: hvec[j] = dot(W_hh[j,:], hid) + b_hh[j] + b_ih[j]
    const int j = (bid - 3488) * 4 + (tid >> 6);
    const int lane = tid & 63;
    const float* w = Whh + (size_t)j * 512;
    float s = 0.f;
    for (int k = lane; k < 512; k += 64) s += w[k] * hid[k];
    for (int off = 32; off; off >>= 1) s += __shfl_down(s, off, 64);
    if (lane == 0) hvec[j] = s + bhh[j] + bih[j];
  }
}

// ---------- GEMM1: X8 = fp8(relu(A0 @ W1^T + b1) * 8), operand-tiled out ----------
__global__ __launch_bounds__(256, 2) void gemm1_relu(
    const unsigned short* __restrict__ A0,   // [32768,544] bf16
    const unsigned short* __restrict__ W1b,  // [512,544] bf16
    const float* __restrict__ b1,            // [512]
    unsigned char* __restrict__ X8) {        // [32768,512] fp8 (x8, operand-tiled)
  constexpr int KT = 17, LD = 544;
  __shared__ __align__(16) unsigned short As[2][128 * 32];  // 16 KB
  __shared__ __align__(16) unsigned short Bs[2][128 * 32];  // 16 KB
  const int tid = threadIdx.x, wave = tid >> 6, lane = tid & 63;
  const int id = blockIdx.x, xcd = id & 7, slot = id >> 3;  // 1024 blocks
  const int m0 = (xcd * 32 + (slot >> 2)) * 128;            // 256 m-tiles
  const int n0 = (slot & 3) * 128;                          // 4 n-tiles
  const int wr = (wave >> 1) * 64, wc = (wave & 1) * 64;
  f32x4 acc[4][4] = {};

  const int c0 = tid, c1 = tid + 256;
  const unsigned short* pA0 = A0 + (size_t)(m0 + (c0 >> 2)) * LD + swz_col(c0);
  const unsigned short* pA1 = A0 + (size_t)(m0 + (c1 >> 2)) * LD + swz_col(c1);
  const unsigned short* pB0 = W1b + (size_t)(n0 + (c0 >> 2)) * LD + swz_col(c0);
  const unsigned short* pB1 = W1b + (size_t)(n0 + (c1 >> 2)) * LD + swz_col(c1);
  const int fr = lane & 15, q = lane >> 4;
  const int koff = (q ^ ((fr >> 1) & 3)) * 8;

#define STAGE1(buf)                                                            \
  do {                                                                         \
    GLD_LDS16(pA0, &As[(buf)][wave * 512]);                                    \
    GLD_LDS16(pA1, &As[(buf)][2048 + wave * 512]);                             \
    GLD_LDS16(pB0, &Bs[(buf)][wave * 512]);                                    \
    GLD_LDS16(pB1, &Bs[(buf)][2048 + wave * 512]);                             \
    pA0 += 32; pA1 += 32; pB0 += 32; pB1 += 32;                                \
  } while (0)

  STAGE1(0);
  for (int kt = 0; kt < KT; ++kt) {
    if (kt + 1 < KT) { STAGE1((kt + 1) & 1); TOPBAR_4; } else { TOPBAR_0; }
    const unsigned short* as = As[kt & 1];
    const unsigned short* bs = Bs[kt & 1];
    bf16x8 a[4], b[4];
#pragma unroll
    for (int i = 0; i < 4; ++i) a[i] = *(const bf16x8*)&as[(wr + i * 16 + fr) * 32 + koff];
#pragma unroll
    for (int j = 0; j < 4; ++j) b[j] = *(const bf16x8*)&bs[(wc + j * 16 + fr) * 32 + koff];
#pragma unroll
    for (int i = 0; i < 4; ++i)
#pragma unroll
      for (int j = 0; j < 4; ++j)
        acc[i][j] = __builtin_amdgcn_mfma_f32_16x16x32_bf16(a[i], b[j], acc[i][j], 0, 0, 0);
    BOTBAR;
  }
#undef STAGE1
  const int rbase = q * 4, cn = fr;
#pragma unroll
  for (int i = 0; i < 4; ++i)
#pragma unroll
    for (int j = 0; j < 4; ++j) {
      const int gn = n0 + wc + j * 16 + cn;
      const float bias = b1[gn];
#pragma unroll
      for (int r = 0; r < 4; ++r) {
        const int gm = m0 + wr + i * 16 + rbase + r;
        float v = acc[i][j][r] + bias;
        v = v > 0.f ? v : 0.f;
        X8[opt_off(gm, gn)] = f2fp8(v * 8.f);
      }
    }
}

// ---------- GEMM2 MX-fp8 32x32x64, ZERO-LDS direct-to-register + LSTM epilogue --
// A = X8 (x8), B = Wih8 (x16), both operand-tiled (opt_off); unit E8M0 scales;
// acc * (1/128) restores scale. Wave owns 64 rows (2 A-frags) x 32 cols x 4
// gate quadrants = 8 MFMAs/kt.
//
// NO LDS, NO BARRIERS: operand-tiled layout makes each lane's MFMA operand a
// direct coalesced global load (wave = 1024 contiguous B per dwordx4). A-rows
// are used by exactly one wave (no sharing -> LDS gained nothing); B (8 KB/kt)
// is shared by 4 waves via L1/L2 (same-m-tile blocks pinned to one XCD by the
// id&7 swizzle -> X8 panel L2-local). A double-buffered in regs (prefetch
// kt+1 issued before kt's MFMAs -> compiler emits counted vmcnt); B loaded at
// top of each kt. Removes the 2-barrier-per-kt drain that capped R5 at 26%
// MfmaUtil with only 2 waves/SIMD resident.
//
// Register budget at __launch_bounds__(256,2) (256 regs/wave): acc 128 +
// A cur/nxt 32 + B 48 + addresses/misc ~25 = ~230. Do NOT raise to 3 (R4:
// acc spill -> FETCH 295 MB / WRITE 600 MB / 3.3x).
// Operand layout (32x32x64 f8f6f4): lane l holds row l&31, k=(l>>5)*32+[0..31].
// C/D: col=lane&31, row=(reg&3)+8*(reg>>2)+4*(lane>>5)  (shape-determined).
__global__ __launch_bounds__(256, 2) void gemm2_lstm(
    const unsigned char* __restrict__ X8,    // [32768,512] fp8, operand-tiled
    const unsigned char* __restrict__ Wih8,  // [2048,512] fp8, operand-tiled
    const float* __restrict__ hvec,          // [2048]
    const float* __restrict__ cell,          // [512]
    unsigned short* __restrict__ H,          // [32768,512] bf16 out
    float* __restrict__ hlast,               // [512] fp32 out
    float* __restrict__ clast) {             // [512] fp32 out
  const int tid = threadIdx.x, wave = tid >> 6, lane = tid & 63;
  const int id = blockIdx.x, xcd = id & 7, slot = id >> 3;  // 2048 blocks
  const int m0 = (xcd * 16 + (slot >> 4)) * 256;            // 128 m-tiles
  const int n0 = (slot & 15) * 32;                          // 16 quadrant-col tiles
  const int r31 = lane & 31, g2 = lane >> 5;
  const int voff = g2 * 512 + r31 * 16;  // lane's operand offset within a panel

  // 8 accumulators: [frag f=0,1][gate quadrant 0..3]
  f32x16 acc00 = {}, acc01 = {}, acc02 = {}, acc03 = {};
  f32x16 acc10 = {}, acc11 = {}, acc12 = {}, acc13 = {};

  // panel base pointers (advance +2048 per kt; rowblock stride 16384)
  const unsigned char* pa0 = X8 + (size_t)((m0 >> 5) + wave * 2 + 0) * 16384 + voff;
  const unsigned char* pa1 = X8 + (size_t)((m0 >> 5) + wave * 2 + 1) * 16384 + voff;
  const unsigned char* pb0 = Wih8 + (size_t)(0 * 16 + (n0 >> 5)) * 16384 + voff;
  const unsigned char* pb1 = Wih8 + (size_t)(1 * 16 + (n0 >> 5)) * 16384 + voff;
  const unsigned char* pb2 = Wih8 + (size_t)(2 * 16 + (n0 >> 5)) * 16384 + voff;
  const unsigned char* pb3 = Wih8 + (size_t)(3 * 16 + (n0 >> 5)) * 16384 + voff;

#define LD8(dst, p)                                                            \
  do {                                                                         \
    i32x4 lo_ = *(const i32x4*)(p);                                            \
    i32x4 hi_ = *(const i32x4*)((p) + 1024);                                   \
    dst = __builtin_shufflevector(lo_, hi_, 0, 1, 2, 3, 4, 5, 6, 7);           \
  } while (0)

#define MFMA_MX(acc_, a_, b_)                                                  \
  acc_ = __builtin_amdgcn_mfma_scale_f32_32x32x64_f8f6f4(                      \
      a_, b_, acc_, 0, 0, 0, 0x7f7f7f7f, 0, 0x7f7f7f7f)

  i32x8 A0, A1;
  LD8(A0, pa0); LD8(A1, pa1);
#pragma unroll
  for (int kt = 0; kt < 8; ++kt) {
    i32x8 B0, B1, B2, B3;
    LD8(B0, pb0); LD8(B1, pb1); LD8(B2, pb2); LD8(B3, pb3);
    pb0 += 2048; pb1 += 2048; pb2 += 2048; pb3 += 2048;
    i32x8 nA0, nA1;
    if (kt < 7) {
      pa0 += 2048; pa1 += 2048;
      LD8(nA0, pa0); LD8(nA1, pa1);
    }
    MFMA_MX(acc00, A0, B0); MFMA_MX(acc01, A0, B1);
    MFMA_MX(acc02, A0, B2); MFMA_MX(acc03, A0, B3);
    MFMA_MX(acc10, A1, B0); MFMA_MX(acc11, A1, B1);
    MFMA_MX(acc12, A1, B2); MFMA_MX(acc13, A1, B3);
    if (kt < 7) { A0 = nA0; A1 = nA1; }
  }

  const int gn = n0 + r31;  // column in [0,512)
  const float hv_i = hvec[gn];
  const float hv_f = hvec[gn + 512];
  const float hv_g = hvec[gn + 1024];
  const float hv_o = hvec[gn + 1536];
  const float cprev = cell[gn];
  constexpr float S = 1.f / 128.f;  // undo x8 (X) * x16 (Wih)

#define EPILOG(F, ai, af, ag, ao)                                              \
  _Pragma("unroll")                                                            \
  for (int rg = 0; rg < 4; ++rg) {                                             \
    _Pragma("unroll")                                                          \
    for (int rr = 0; rr < 4; ++rr) {                                           \
      const int reg = rg * 4 + rr;                                             \
      const int gm = m0 + wave * 64 + (F) * 32 + rr + rg * 8 + g2 * 4;         \
      float si = sigm(ai[reg] * S + hv_i);                                     \
      float sf = sigm(af[reg] * S + hv_f);                                     \
      float tg = tanh_(ag[reg] * S + hv_g);                                    \
      float so = sigm(ao[reg] * S + hv_o);                                     \
      float cnew = sf * cprev + si * tg;                                       \
      float hnew = so * tanh_(cnew);                                           \
      H[(size_t)gm * 512 + gn] = f2bf(hnew);                                   \
      if (gm == 32767) { hlast[gn] = hnew; clast[gn] = cnew; }                 \
    }                                                                          \
  }

  EPILOG(0, acc00, acc01, acc02, acc03)
  EPILOG(1, acc10, acc11, acc12, acc13)
#undef EPILOG
#undef LD8
#undef MFMA_MX
}

// ---------- GEMM3: Q = H @ W2^T + b2 (64-row tiles, 512 blocks) ----------
__global__ __launch_bounds__(256, 2) void gemm3(
    const unsigned short* __restrict__ H,    // [32768,512] bf16
    const unsigned short* __restrict__ W2b,  // [32,512] bf16
    const float* __restrict__ b2,            // [32]
    float* __restrict__ Q) {                 // [32768,32] fp32
  constexpr int KT = 16, LDW = 520;
  __shared__ __align__(16) unsigned short As[2][64 * 32];    // 8 KB
  __shared__ __align__(16) unsigned short Ws[32 * LDW];      // 32.5 KB
  const int tid = threadIdx.x, wave = tid >> 6, lane = tid & 63;
  const int id = blockIdx.x;                                 // 512 blocks
  const int m0 = ((id & 7) * 64 + (id >> 3)) * 64;           // 64-row tiles
  for (int c = tid; c < 2048; c += 256) {
    const int row = c >> 6, col8 = c & 63;
    *(uint4*)&Ws[row * LDW + col8 * 8] = *(const uint4*)(W2b + row * 512 + col8 * 8);
  }
  f32x4 acc[2] = {};
  const int c0 = tid;
  const unsigned short* pA0 = H + (size_t)(m0 + (c0 >> 2)) * 512 + swz_col(c0);
  const int fr = lane & 15, q = lane >> 4;
  const int koff = (q ^ ((fr >> 1) & 3)) * 8;

#define STAGE3(buf)                                                            \
  do {                                                                         \
    GLD_LDS16(pA0, &As[(buf)][wave * 512]);                                    \
    pA0 += 32;                                                                 \
  } while (0)

  STAGE3(0);
  for (int kt = 0; kt < KT; ++kt) {
    if (kt + 1 < KT) { STAGE3((kt + 1) & 1); TOPBAR_1; } else { TOPBAR_0; }
    const unsigned short* as = As[kt & 1];
    const int k0 = kt * 32;
    bf16x8 a  = *(const bf16x8*)&as[(wave * 16 + fr) * 32 + koff];
    bf16x8 b0 = *(const bf16x8*)&Ws[fr * LDW + k0 + q * 8];
    bf16x8 b1 = *(const bf16x8*)&Ws[(16 + fr) * LDW + k0 + q * 8];
    acc[0] = __builtin_amdgcn_mfma_f32_16x16x32_bf16(a, b0, acc[0], 0, 0, 0);
    acc[1] = __builtin_amdgcn_mfma_f32_16x16x32_bf16(a, b1, acc[1], 0, 0, 0);
    BOTBAR;
  }
#undef STAGE3
  const int rbase = q * 4;
#pragma unroll
  for (int j = 0; j < 2; ++j) {
    const int gn = j * 16 + fr;
    const float bias = b2[gn];
#pragma unroll
    for (int r = 0; r < 4; ++r) {
      const int gm = m0 + wave * 16 + rbase + r;
      Q[(size_t)gm * 32 + gn] = acc[j][r] + bias;
    }
  }
}

// ---------- launch ----------
extern "C" void kernel_launch(void* const* d_in, const int* in_sizes, int n_in,
                              void* d_out, int out_size, void* d_ws, size_t ws_size,
                              hipStream_t stream) {
  const float* obs  = (const float*)d_in[0];
  const float* act  = (const float*)d_in[1];
  const float* hid  = (const float*)d_in[2];
  const float* cell = (const float*)d_in[3];
  const float* W1   = (const float*)d_in[4];
  const float* b1   = (const float*)d_in[5];
  const float* Wih  = (const float*)d_in[6];
  const float* bih  = (const float*)d_in[7];
  const float* Whh  = (const float*)d_in[8];
  const float* bhh  = (const float*)d_in[9];
  const float* W2   = (const float*)d_in[10];
  const float* b2   = (const float*)d_in[11];
  float* out = (float*)d_out;

  char* ws = (char*)d_ws;
  unsigned short* A0   = (unsigned short*)(ws);              // [B,544] bf16 (35,651,584 B)
  unsigned short* H    = (unsigned short*)(ws);              // alias A0 (dead after gemm1)
  unsigned char*  X8   = (unsigned char*)(ws + 35651584);    // [B,512] fp8 tiled (16,777,216 B)
  unsigned short* W1b  = (unsigned short*)(ws + 52428800);   // 557,056 B
  unsigned char*  Wih8 = (unsigned char*)(ws + 52985856);    // 1,048,576 B
  unsigned short* W2b  = (unsigned short*)(ws + 54034432);   // 32,768 B
  float*          hvec = (float*)(ws + 54067200);            // 8,192 B

  prep_all<<<4000, 256, 0, stream>>>(obs, act, W1, Wih, W2, Whh, hid, bhh, bih,
                                     A0, W1b, Wih8, W2b, hvec);
  gemm1_relu<<<1024, 256, 0, stream>>>(A0, W1b, b1, X8);
  gemm2_lstm<<<2048, 256, 0, stream>>>(X8, Wih8, hvec, cell, H,
                                       out + 32768 * 32,
                                       out + 32768 * 32 + 512);
  gemm3<<<512, 256, 0, stream>>>(H, W2b, b2, out);
}

// Round 7
// 204.960 us; speedup vs baseline: 1.7207x; 1.0211x over previous
//
#include <hip/hip_runtime.h>
#include <stdint.h>

#define DEVINL __device__ __forceinline__

typedef __attribute__((ext_vector_type(8))) __bf16 bf16x8;
typedef __attribute__((ext_vector_type(4))) float f32x4;
typedef __attribute__((ext_vector_type(16))) float f32x16;
typedef __attribute__((ext_vector_type(4))) int i32x4;
typedef __attribute__((ext_vector_type(8))) int i32x8;

// ---------- helpers ----------
DEVINL unsigned short f2bf(float f) {
  union { float f; unsigned int u; } v; v.f = f;
  unsigned int u = v.u;
  return (unsigned short)((u + 0x7fffu + ((u >> 16) & 1u)) >> 16);  // RNE
}

// float -> OCP e4m3 byte via HW cvt (gfx950 = OCP semantics)
DEVINL unsigned char f2fp8(float f) {
  return (unsigned char)(__builtin_amdgcn_cvt_pk_fp8_f32(f, f, 0, false) & 0xff);
}

DEVINL float sigm(float x) { return __builtin_amdgcn_rcpf(1.f + __expf(-x)); }
// tanh = 1 - 2/(1+e^{2x}); inf-safe both directions.
DEVINL float tanh_(float x) {
  return 1.f - 2.f * __builtin_amdgcn_rcpf(1.f + __expf(2.f * x));
}

// Operand-order ("tiled") global layout for gemm2's fp8 operands.
// 2048-B panel per (32-row block, 64-k block): [h=(k>>4)&1][g=(k>>5)&1][row&31][k&15]
// Lane l (r31=l&31, g2=l>>5) of a 32x32x64 MFMA needs k = g2*32+[0..31]:
// lo 16B at panel + g2*512 + r31*16, hi 16B at +1024. A wave's 64 lanes cover
// 1024 contiguous bytes per half -> coalesced, bytes land directly in MFMA
// operand order. For a fixed 32-row block, the 8 K-panels are CONTIGUOUS
// (16 KB) -> whole-K staging is 16 back-to-back 1KB gload_lds.
DEVINL size_t opt_off(int row, int k) {
  return (size_t)((row >> 5) * 8 + (k >> 6)) * 2048 + ((k >> 4) & 1) * 1024 +
         ((k >> 5) & 1) * 512 + (row & 31) * 16 + (k & 15);
}

// async global->LDS 16B per lane; lds base wave-uniform, HW scatters lane i to base+i*16
#define GLD_LDS16(gptr, lptr)                                                  \
  __builtin_amdgcn_global_load_lds(                                            \
      (__attribute__((address_space(1))) void*)(gptr),                         \
      (__attribute__((address_space(3))) void*)(lptr), 16, 0, 0)

// Stage-before-barrier pipeline (gemm1/gemm3): STAGE(k+1) issued BEFORE the
// top barrier; TOPBAR_N waits vmcnt(N). Last iter peels to vmcnt(0).
#define TOPBAR_4 asm volatile("s_waitcnt vmcnt(4) lgkmcnt(0)\n\ts_barrier" ::: "memory")
#define TOPBAR_1 asm volatile("s_waitcnt vmcnt(1) lgkmcnt(0)\n\ts_barrier" ::: "memory")
#define TOPBAR_0 asm volatile("s_waitcnt vmcnt(0) lgkmcnt(0)\n\ts_barrier" ::: "memory")
#define BOTBAR   asm volatile("s_waitcnt lgkmcnt(0)\n\ts_barrier" ::: "memory")

// bf16-path XOR swizzle (gemm1/gemm3, unchanged; measured 0-conflict): staging
// chunk c takes source chunk (c&3)^((c>>3)&3); read koff = (q ^ ((fr>>1)&3)).
DEVINL int swz_col(int c) { return ((c & 3) ^ ((c >> 3) & 3)) * 8; }   // bf16: *8 shorts = 16B

// ---------- fused prep: input concat + weight cvt + hvec, grid-sectioned ----------
__global__ void prep_all(const float* __restrict__ obs, const float* __restrict__ act,
                         const float* __restrict__ W1, const float* __restrict__ Wih,
                         const float* __restrict__ W2, const float* __restrict__ Whh,
                         const float* __restrict__ hid, const float* __restrict__ bhh,
                         const float* __restrict__ bih,
                         unsigned short* __restrict__ A0, unsigned short* __restrict__ W1b,
                         unsigned char* __restrict__ Wih8, unsigned short* __restrict__ W2b,
                         float* __restrict__ hvec) {
  const int bid = blockIdx.x, tid = threadIdx.x;
  if (bid < 2176) {
    // section A: concat(obs, act) -> bf16 [32768, 544]
    const int total = 32768 * 68;
    for (int c = bid * 256 + tid; c < total; c += 2176 * 256) {
      const int b = c / 68, c8 = c % 68;
      const float* src = (c8 < 64) ? (obs + (size_t)b * 512 + c8 * 8)
                                   : (act + (size_t)b * 32 + (c8 - 64) * 8);
      float4 f0 = *(const float4*)src;
      float4 f1 = *(const float4*)(src + 4);
      unsigned short u[8] = {f2bf(f0.x), f2bf(f0.y), f2bf(f0.z), f2bf(f0.w),
                             f2bf(f1.x), f2bf(f1.y), f2bf(f1.z), f2bf(f1.w)};
      *(uint4*)(A0 + (size_t)b * 544 + c8 * 8) = *(uint4*)u;
    }
  } else if (bid < 2176 + 1312) {
    // section B: weight conversion (one float4 per thread)
    const int i = (bid - 2176) * 256 + tid;
    if (i < 69632) {                       // W1 -> bf16
      float4 f = *(const float4*)(W1 + (size_t)i * 4);
      unsigned short u[4] = {f2bf(f.x), f2bf(f.y), f2bf(f.z), f2bf(f.w)};
      *(uint2*)(W1b + (size_t)i * 4) = *(uint2*)u;
    } else if (i < 69632 + 262144) {       // Wih -> fp8 e4m3 x16, operand-tiled layout
      const int off = i - 69632;
      const int row = off >> 7, col0 = (off & 127) * 4;  // 4 consecutive cols, same 16B chunk
      float4 f = *(const float4*)(Wih + (size_t)off * 4);
      int pk = __builtin_amdgcn_cvt_pk_fp8_f32(f.x * 16.f, f.y * 16.f, 0, false);
      pk = __builtin_amdgcn_cvt_pk_fp8_f32(f.z * 16.f, f.w * 16.f, pk, true);
      *(unsigned int*)(Wih8 + opt_off(row, col0)) = (unsigned int)pk;
    } else {                               // W2 -> bf16
      const int off = i - 331776;
      float4 f = *(const float4*)(W2 + (size_t)off * 4);
      unsigned short u[4] = {f2bf(f.x), f2bf(f.y), f2bf(f.z), f2bf(f.w)};
      *(uint2*)(W2b + (size_t)off * 4) = *(uint2*)u;
    }
  } else {
    // section C: hvec[j] = dot(W_hh[j,:], hid) + b_hh[j] + b_ih[j]
    const int j = (bid - 3488) * 4 + (tid >> 6);
    const int lane = tid & 63;
    const float* w = Whh + (size_t)j * 512;
    float s = 0.f;
    for (int k = lane; k < 512; k += 64) s += w[k] * hid[k];
    for (int off = 32; off; off >>= 1) s += __shfl_down(s, off, 64);
    if (lane == 0) hvec[j] = s + bhh[j] + bih[j];
  }
}

// ---------- GEMM1: X8 = fp8(relu(A0 @ W1^T + b1) * 8), operand-tiled out ----------
__global__ __launch_bounds__(256, 2) void gemm1_relu(
    const unsigned short* __restrict__ A0,   // [32768,544] bf16
    const unsigned short* __restrict__ W1b,  // [512,544] bf16
    const float* __restrict__ b1,            // [512]
    unsigned char* __restrict__ X8) {        // [32768,512] fp8 (x8, operand-tiled)
  constexpr int KT = 17, LD = 544;
  __shared__ __align__(16) unsigned short As[2][128 * 32];  // 16 KB
  __shared__ __align__(16) unsigned short Bs[2][128 * 32];  // 16 KB
  const int tid = threadIdx.x, wave = tid >> 6, lane = tid & 63;
  const int id = blockIdx.x, xcd = id & 7, slot = id >> 3;  // 1024 blocks
  const int m0 = (xcd * 32 + (slot >> 2)) * 128;            // 256 m-tiles
  const int n0 = (slot & 3) * 128;                          // 4 n-tiles
  const int wr = (wave >> 1) * 64, wc = (wave & 1) * 64;
  f32x4 acc[4][4] = {};

  const int c0 = tid, c1 = tid + 256;
  const unsigned short* pA0 = A0 + (size_t)(m0 + (c0 >> 2)) * LD + swz_col(c0);
  const unsigned short* pA1 = A0 + (size_t)(m0 + (c1 >> 2)) * LD + swz_col(c1);
  const unsigned short* pB0 = W1b + (size_t)(n0 + (c0 >> 2)) * LD + swz_col(c0);
  const unsigned short* pB1 = W1b + (size_t)(n0 + (c1 >> 2)) * LD + swz_col(c1);
  const int fr = lane & 15, q = lane >> 4;
  const int koff = (q ^ ((fr >> 1) & 3)) * 8;

#define STAGE1(buf)                                                            \
  do {                                                                         \
    GLD_LDS16(pA0, &As[(buf)][wave * 512]);                                    \
    GLD_LDS16(pA1, &As[(buf)][2048 + wave * 512]);                             \
    GLD_LDS16(pB0, &Bs[(buf)][wave * 512]);                                    \
    GLD_LDS16(pB1, &Bs[(buf)][2048 + wave * 512]);                             \
    pA0 += 32; pA1 += 32; pB0 += 32; pB1 += 32;                                \
  } while (0)

  STAGE1(0);
  for (int kt = 0; kt < KT; ++kt) {
    if (kt + 1 < KT) { STAGE1((kt + 1) & 1); TOPBAR_4; } else { TOPBAR_0; }
    const unsigned short* as = As[kt & 1];
    const unsigned short* bs = Bs[kt & 1];
    bf16x8 a[4], b[4];
#pragma unroll
    for (int i = 0; i < 4; ++i) a[i] = *(const bf16x8*)&as[(wr + i * 16 + fr) * 32 + koff];
#pragma unroll
    for (int j = 0; j < 4; ++j) b[j] = *(const bf16x8*)&bs[(wc + j * 16 + fr) * 32 + koff];
#pragma unroll
    for (int i = 0; i < 4; ++i)
#pragma unroll
      for (int j = 0; j < 4; ++j)
        acc[i][j] = __builtin_amdgcn_mfma_f32_16x16x32_bf16(a[i], b[j], acc[i][j], 0, 0, 0);
    BOTBAR;
  }
#undef STAGE1
  const int rbase = q * 4, cn = fr;
#pragma unroll
  for (int i = 0; i < 4; ++i)
#pragma unroll
    for (int j = 0; j < 4; ++j) {
      const int gn = n0 + wc + j * 16 + cn;
      const float bias = b1[gn];
#pragma unroll
      for (int r = 0; r < 4; ++r) {
        const int gm = m0 + wr + i * 16 + rbase + r;
        float v = acc[i][j][r] + bias;
        v = v > 0.f ? v : 0.f;
        X8[opt_off(gm, gn)] = f2fp8(v * 8.f);
      }
    }
}

// ---------- GEMM2 MX-fp8 32x32x64: B-in-LDS-once + deep-prefetch A + LSTM ------
// A = X8 (x8), B = Wih8 (x16), operand-tiled (opt_off); unit E8M0 scales;
// acc * (1/128) restores scale. Wave owns 64 rows (2 A-frags) x 32 cols x 4
// gate quadrants = 8 MFMAs/kt.
//
// Structure (fixes R6's 26% MfmaUtil):
//  - B (64 KB for ALL 8 kt) staged ONCE into LDS in the prologue: wave w
//    stages quad w's contiguous 16 KB via 16 gload_lds; ONE __syncthreads();
//    the kt-loop reads B with lane-linear ds_read_b128 (zero conflicts, zero
//    barriers, and kills the 8x per-wave re-load of block-uniform B that cost
//    ~536 MB of L1/L2 traffic in R6).
//  - A direct-to-register, TRIPLE-buffered (prefetch kt+2): R6's 1-kt lead
//    (~200 cyc) was far short of HBM latency (~900 cyc; FETCH=12.4 MB shows
//    X8 misses L2 -- H's 33 MB write-through evicts it).
//
// Register budget at __launch_bounds__(256,2) (256/wave): acc 128 + A 3x16 +
// B 32 + addr ~25 = ~233. Do NOT raise occupancy (R4: spill -> FETCH 295 MB).
// Operand layout (32x32x64 f8f6f4): lane l holds row l&31, k=(l>>5)*32+[0..31].
// C/D: col=lane&31, row=(reg&3)+8*(reg>>2)+4*(lane>>5)  (shape-determined).
__global__ __launch_bounds__(256, 2) void gemm2_lstm(
    const unsigned char* __restrict__ X8,    // [32768,512] fp8, operand-tiled
    const unsigned char* __restrict__ Wih8,  // [2048,512] fp8, operand-tiled
    const float* __restrict__ hvec,          // [2048]
    const float* __restrict__ cell,          // [512]
    unsigned short* __restrict__ H,          // [32768,512] bf16 out
    float* __restrict__ hlast,               // [512] fp32 out
    float* __restrict__ clast) {             // [512] fp32 out
  __shared__ __align__(16) unsigned char Bs[4 * 16384];      // 64 KB: [quad][kt*2048+h*1024]
  const int tid = threadIdx.x, wave = tid >> 6, lane = tid & 63;
  const int id = blockIdx.x, xcd = id & 7, slot = id >> 3;  // 2048 blocks
  const int m0 = (xcd * 16 + (slot >> 4)) * 256;            // 128 m-tiles
  const int n0 = (slot & 15) * 32;                          // 16 quadrant-col tiles
  const int r31 = lane & 31, g2 = lane >> 5;
  const int voff = g2 * 512 + r31 * 16;  // lane's operand offset within a panel

  // ---- prologue: stage ALL of B (this block's 4 quads x 8 kt) into LDS ----
  // wave w stages quad w: source rowblock (w*16 + n0>>5) = 16 KB contiguous.
  {
    const unsigned char* bsrc =
        Wih8 + (size_t)(wave * 16 + (n0 >> 5)) * 16384 + lane * 16;
#pragma unroll
    for (int s = 0; s < 16; ++s)
      GLD_LDS16(bsrc + s * 1024, &Bs[wave * 16384 + s * 1024]);
  }

  // ---- A prefetch (triple-buffered, depth 2) ----
  const unsigned char* pa = X8 + (size_t)((m0 >> 5) + wave * 2) * 16384 + voff;
  i32x8 Aa[3], Ab[3];
#define LDA(buf, kt)                                                           \
  do {                                                                         \
    i32x4 lo0 = *(const i32x4*)(pa + (kt) * 2048);                             \
    i32x4 hi0 = *(const i32x4*)(pa + (kt) * 2048 + 1024);                      \
    Aa[buf] = __builtin_shufflevector(lo0, hi0, 0, 1, 2, 3, 4, 5, 6, 7);       \
    i32x4 lo1 = *(const i32x4*)(pa + 16384 + (kt) * 2048);                     \
    i32x4 hi1 = *(const i32x4*)(pa + 16384 + (kt) * 2048 + 1024);              \
    Ab[buf] = __builtin_shufflevector(lo1, hi1, 0, 1, 2, 3, 4, 5, 6, 7);       \
  } while (0)

#define MFMA_MX(acc_, a_, b_)                                                  \
  acc_ = __builtin_amdgcn_mfma_scale_f32_32x32x64_f8f6f4(                      \
      a_, b_, acc_, 0, 0, 0, 0x7f7f7f7f, 0, 0x7f7f7f7f)

  LDA(0, 0);
  LDA(1, 1);
  __syncthreads();  // B visible (vmcnt(0)+lgkmcnt(0) drain + barrier); only barrier in kernel

  // 8 accumulators: [frag f=0,1][gate quadrant 0..3]
  f32x16 acc00 = {}, acc01 = {}, acc02 = {}, acc03 = {};
  f32x16 acc10 = {}, acc11 = {}, acc12 = {}, acc13 = {};

#pragma unroll
  for (int kt = 0; kt < 8; ++kt) {
    const int cur = kt % 3, nx = (kt + 2) % 3;  // compile-time after unroll
    if (kt < 6) LDA(nx, kt + 2);                // issue-early: 2-kt lead on HBM
    i32x8 B0, B1, B2, B3;
    {
      const unsigned char* bb = &Bs[kt * 2048 + lane * 16];
      i32x4 l0 = *(const i32x4*)(bb);
      i32x4 h0 = *(const i32x4*)(bb + 1024);
      i32x4 l1 = *(const i32x4*)(bb + 16384);
      i32x4 h1 = *(const i32x4*)(bb + 16384 + 1024);
      i32x4 l2 = *(const i32x4*)(bb + 32768);
      i32x4 h2 = *(const i32x4*)(bb + 32768 + 1024);
      i32x4 l3 = *(const i32x4*)(bb + 49152);
      i32x4 h3 = *(const i32x4*)(bb + 49152 + 1024);
      B0 = __builtin_shufflevector(l0, h0, 0, 1, 2, 3, 4, 5, 6, 7);
      B1 = __builtin_shufflevector(l1, h1, 0, 1, 2, 3, 4, 5, 6, 7);
      B2 = __builtin_shufflevector(l2, h2, 0, 1, 2, 3, 4, 5, 6, 7);
      B3 = __builtin_shufflevector(l3, h3, 0, 1, 2, 3, 4, 5, 6, 7);
    }
    MFMA_MX(acc00, Aa[cur], B0); MFMA_MX(acc01, Aa[cur], B1);
    MFMA_MX(acc02, Aa[cur], B2); MFMA_MX(acc03, Aa[cur], B3);
    MFMA_MX(acc10, Ab[cur], B0); MFMA_MX(acc11, Ab[cur], B1);
    MFMA_MX(acc12, Ab[cur], B2); MFMA_MX(acc13, Ab[cur], B3);
  }
#undef LDA
#undef MFMA_MX

  const int gn = n0 + r31;  // column in [0,512)
  const float hv_i = hvec[gn];
  const float hv_f = hvec[gn + 512];
  const float hv_g = hvec[gn + 1024];
  const float hv_o = hvec[gn + 1536];
  const float cprev = cell[gn];
  constexpr float S = 1.f / 128.f;  // undo x8 (X) * x16 (Wih)

#define EPILOG(F, ai, af, ag, ao)                                              \
  _Pragma("unroll")                                                            \
  for (int rg = 0; rg < 4; ++rg) {                                             \
    _Pragma("unroll")                                                          \
    for (int rr = 0; rr < 4; ++rr) {                                           \
      const int reg = rg * 4 + rr;                                             \
      const int gm = m0 + wave * 64 + (F) * 32 + rr + rg * 8 + g2 * 4;         \
      float si = sigm(ai[reg] * S + hv_i);                                     \
      float sf = sigm(af[reg] * S + hv_f);                                     \
      float tg = tanh_(ag[reg] * S + hv_g);                                    \
      float so = sigm(ao[reg] * S + hv_o);                                     \
      float cnew = sf * cprev + si * tg;                                       \
      float hnew = so * tanh_(cnew);                                           \
      H[(size_t)gm * 512 + gn] = f2bf(hnew);                                   \
      if (gm == 32767) { hlast[gn] = hnew; clast[gn] = cnew; }                 \
    }                                                                          \
  }

  EPILOG(0, acc00, acc01, acc02, acc03)
  EPILOG(1, acc10, acc11, acc12, acc13)
#undef EPILOG
}

// ---------- GEMM3: Q = H @ W2^T + b2 (64-row tiles, 512 blocks) ----------
__global__ __launch_bounds__(256, 2) void gemm3(
    const unsigned short* __restrict__ H,    // [32768,512] bf16
    const unsigned short* __restrict__ W2b,  // [32,512] bf16
    const float* __restrict__ b2,            // [32]
    float* __restrict__ Q) {                 // [32768,32] fp32
  constexpr int KT = 16, LDW = 520;
  __shared__ __align__(16) unsigned short As[2][64 * 32];    // 8 KB
  __shared__ __align__(16) unsigned short Ws[32 * LDW];      // 32.5 KB
  const int tid = threadIdx.x, wave = tid >> 6, lane = tid & 63;
  const int id = blockIdx.x;                                 // 512 blocks
  const int m0 = ((id & 7) * 64 + (id >> 3)) * 64;           // 64-row tiles
  for (int c = tid; c < 2048; c += 256) {
    const int row = c >> 6, col8 = c & 63;
    *(uint4*)&Ws[row * LDW + col8 * 8] = *(const uint4*)(W2b + row * 512 + col8 * 8);
  }
  f32x4 acc[2] = {};
  const int c0 = tid;
  const unsigned short* pA0 = H + (size_t)(m0 + (c0 >> 2)) * 512 + swz_col(c0);
  const int fr = lane & 15, q = lane >> 4;
  const int koff = (q ^ ((fr >> 1) & 3)) * 8;

#define STAGE3(buf)                                                            \
  do {                                                                         \
    GLD_LDS16(pA0, &As[(buf)][wave * 512]);                                    \
    pA0 += 32;                                                                 \
  } while (0)

  STAGE3(0);
  for (int kt = 0; kt < KT; ++kt) {
    if (kt + 1 < KT) { STAGE3((kt + 1) & 1); TOPBAR_1; } else { TOPBAR_0; }
    const unsigned short* as = As[kt & 1];
    const int k0 = kt * 32;
    bf16x8 a  = *(const bf16x8*)&as[(wave * 16 + fr) * 32 + koff];
    bf16x8 b0 = *(const bf16x8*)&Ws[fr * LDW + k0 + q * 8];
    bf16x8 b1 = *(const bf16x8*)&Ws[(16 + fr) * LDW + k0 + q * 8];
    acc[0] = __builtin_amdgcn_mfma_f32_16x16x32_bf16(a, b0, acc[0], 0, 0, 0);
    acc[1] = __builtin_amdgcn_mfma_f32_16x16x32_bf16(a, b1, acc[1], 0, 0, 0);
    BOTBAR;
  }
#undef STAGE3
  const int rbase = q * 4;
#pragma unroll
  for (int j = 0; j < 2; ++j) {
    const int gn = j * 16 + fr;
    const float bias = b2[gn];
#pragma unroll
    for (int r = 0; r < 4; ++r) {
      const int gm = m0 + wave * 16 + rbase + r;
      Q[(size_t)gm * 32 + gn] = acc[j][r] + bias;
    }
  }
}

// ---------- launch ----------
extern "C" void kernel_launch(void* const* d_in, const int* in_sizes, int n_in,
                              void* d_out, int out_size, void* d_ws, size_t ws_size,
                              hipStream_t stream) {
  const float* obs  = (const float*)d_in[0];
  const float* act  = (const float*)d_in[1];
  const float* hid  = (const float*)d_in[2];
  const float* cell = (const float*)d_in[3];
  const float* W1   = (const float*)d_in[4];
  const float* b1   = (const float*)d_in[5];
  const float* Wih  = (const float*)d_in[6];
  const float* bih  = (const float*)d_in[7];
  const float* Whh  = (const float*)d_in[8];
  const float* bhh  = (const float*)d_in[9];
  const float* W2   = (const float*)d_in[10];
  const float* b2   = (const float*)d_in[11];
  float* out = (float*)d_out;

  char* ws = (char*)d_ws;
  unsigned short* A0   = (unsigned short*)(ws);              // [B,544] bf16 (35,651,584 B)
  unsigned short* H    = (unsigned short*)(ws);              // alias A0 (dead after gemm1)
  unsigned char*  X8   = (unsigned char*)(ws + 35651584);    // [B,512] fp8 tiled (16,777,216 B)
  unsigned short* W1b  = (unsigned short*)(ws + 52428800);   // 557,056 B
  unsigned char*  Wih8 = (unsigned char*)(ws + 52985856);    // 1,048,576 B
  unsigned short* W2b  = (unsigned short*)(ws + 54034432);   // 32,768 B
  float*          hvec = (float*)(ws + 54067200);            // 8,192 B

  prep_all<<<4000, 256, 0, stream>>>(obs, act, W1, Wih, W2, Whh, hid, bhh, bih,
                                     A0, W1b, Wih8, W2b, hvec);
  gemm1_relu<<<1024, 256, 0, stream>>>(A0, W1b, b1, X8);
  gemm2_lstm<<<2048, 256, 0, stream>>>(X8, Wih8, hvec, cell, H,
                                       out + 32768 * 32,
                                       out + 32768 * 32 + 512);
  gemm3<<<512, 256, 0, stream>>>(H, W2b, b2, out);
}